// Round 6
// baseline (203.759 us; speedup 1.0000x reference)
//
#include <hip/hip_runtime.h>
#include <math.h>

// Problem constants (fixed by reference setup_inputs)
#define NTOT 100
#define NQ   75
#define NP   25
#define CC   128
#define TT   8
#define VV   25
#define NCLS 5
#define NSUP 5
#define NQRY 15
#define ROW  (TT*VV*CC)   // 25600 floats per sample
#define TILE (VV*CC)      // 3200 floats per (n,t)
#define ROWS_Q 20000
#define ROWS_S 5000
#define RB_Q 625
#define RB_S 157

typedef __attribute__((ext_vector_type(8))) short short8;
typedef __attribute__((ext_vector_type(16))) float f32x16;

__device__ __forceinline__ ushort f2bf(float f) {
    uint u = __float_as_uint(f);
    u += 0x7FFFu + ((u >> 16) & 1u);   // RNE
    return (ushort)(u >> 16);
}
__device__ __forceinline__ float bf2f(uint u16v) {
    return __uint_as_float(u16v << 16);
}

// ============ kernel 1: prep ============
// blocks 0..199 : gather half-sample (100 tv rows) -> catC bf16 + bf16 A-frags
// blocks 200..203: weight -> bf16 B-frags; 203 also zeros supp-frag pad + ticket
__global__ __launch_bounds__(256) void k_prep(
    const float* __restrict__ input, const int* __restrict__ target,
    const float* __restrict__ Wq, const float* __restrict__ Wk,
    const float* __restrict__ Wv, const float* __restrict__ Wo,
    ushort* __restrict__ catQbf, ushort* __restrict__ catSbf,
    ushort* __restrict__ Wfrag, ushort* __restrict__ catC,
    int* __restrict__ counter) {
    __shared__ float smp[100 * 129];   // [tt][c], stride 129 conflict-free
    __shared__ int targ[NTOT];
    __shared__ int order[NTOT];
    int b = blockIdx.x, tid = threadIdx.x;

    if (b < 200) {
        int n = b >> 1, hf = b & 1;
        if (tid < NTOT) targ[tid] = target[tid];
        __syncthreads();
        if (tid < NTOT) {
            int ti = targ[tid], rank = 0;
            for (int j = 0; j < NTOT; ++j) {
                int tj = targ[j];
                rank += (tj < ti) || (tj == ti && j < tid);
            }
            order[rank] = tid;
        }
        __syncthreads();
        int src;
        if (n < NQ) { int m = n / NQRY, qq = n - m * NQRY; src = order[m * 20 + NSUP + qq]; }
        else        { int i = n - NQ; int m = i / NSUP, s = i - m * NSUP; src = order[m * 20 + s]; }

        const float* in = input + (size_t)src * ROW + hf * 100;
        for (int idx = tid; idx < 12800; idx += 256) {
            int c = idx / 100, tt = idx - c * 100;      // contiguous 400B runs
            smp[tt * 129 + c] = in[c * 200 + tt];
        }
        __syncthreads();
        // catC bf16 [n][tv][c], packed u32 writes (coalesced)
        uint* cc = (uint*)catC + ((size_t)n * 200 + hf * 100) * 64;
        for (int e2 = tid; e2 < 6400; e2 += 256) {
            int r = e2 >> 6, c2 = e2 & 63;
            float f0 = smp[r * 129 + c2 * 2], f1 = smp[r * 129 + c2 * 2 + 1];
            cc[r * 64 + c2] = (uint)f2bf(f0) | ((uint)f2bf(f1) << 16);
        }
        // bf16 A-frag writes
        bool isSup = (n >= NQ);
        for (int o = tid; o < 1600; o += 256) {
            int k8 = o / 100, tt = o - k8 * 100;
            int base = tt * 129 + k8 * 8;
            uint4 pk;
            pk.x = (uint)f2bf(smp[base+0]) | ((uint)f2bf(smp[base+1]) << 16);
            pk.y = (uint)f2bf(smp[base+2]) | ((uint)f2bf(smp[base+3]) << 16);
            pk.z = (uint)f2bf(smp[base+4]) | ((uint)f2bf(smp[base+5]) << 16);
            pk.w = (uint)f2bf(smp[base+6]) | ((uint)f2bf(smp[base+7]) << 16);
            int row = n * 200 + hf * 100 + tt;
            size_t dst = (((size_t)(row >> 5) * 8 + (k8 >> 1)) * 64 + ((row & 31) + 32 * (k8 & 1))) * 8;
            *(uint4*)(catQbf + dst) = pk;
            if (isSup) {
                int r2 = (n - NQ) * 200 + hf * 100 + tt;
                size_t dst2 = (((size_t)(r2 >> 5) * 8 + (k8 >> 1)) * 64 + ((r2 & 31) + 32 * (k8 & 1))) * 8;
                *(uint4*)(catSbf + dst2) = pk;
            }
        }
    } else {
        int wi = b - 200;
        const float* W = (wi == 0) ? Wq : (wi == 1) ? Wk : (wi == 2) ? Wv : Wo;
        ushort* dstW = Wfrag + (size_t)wi * 16384;
        for (int o = tid; o < 2048; o += 256) {
            int k8 = o >> 7, c = o & 127;
            uint4 pk;
            float f0 = W[(k8*8+0)*128 + c], f1 = W[(k8*8+1)*128 + c];
            float f2 = W[(k8*8+2)*128 + c], f3 = W[(k8*8+3)*128 + c];
            float f4 = W[(k8*8+4)*128 + c], f5 = W[(k8*8+5)*128 + c];
            float f6 = W[(k8*8+6)*128 + c], f7 = W[(k8*8+7)*128 + c];
            pk.x = (uint)f2bf(f0) | ((uint)f2bf(f1) << 16);
            pk.y = (uint)f2bf(f2) | ((uint)f2bf(f3) << 16);
            pk.z = (uint)f2bf(f4) | ((uint)f2bf(f5) << 16);
            pk.w = (uint)f2bf(f6) | ((uint)f2bf(f7) << 16);
            size_t dst = ((size_t)((c >> 5) * 8 + (k8 >> 1)) * 64 + ((c & 31) + 32 * (k8 & 1))) * 8;
            *(uint4*)(dstW + dst) = pk;
        }
        if (wi == 3) {
            uint4 z = make_uint4(0, 0, 0, 0);
            for (int o = tid; o < 512; o += 256) {
                int ks = o >> 6, l = o & 63;
                if ((l & 31) >= 8)
                    *(uint4*)(catSbf + (((size_t)156 * 8 + ks) * 64 + l) * 8) = z;
            }
            if (tid == 0) *counter = 0;
        }
    }
}

// ============ kernel 2: projections via MFMA ============
__global__ __launch_bounds__(256) void k_proj(
    const ushort* __restrict__ catQbf, const ushort* __restrict__ catSbf,
    const ushort* __restrict__ Wfrag, const float* __restrict__ bq,
    const float* __restrict__ bk, const float* __restrict__ bv,
    ushort* __restrict__ Qf, ushort* __restrict__ Kf, ushort* __restrict__ Vf) {
    __shared__ ushort Vt[128 * 136];
    int b = blockIdx.x, tid = threadIdx.x;
    int w = tid >> 6, lane = tid & 63;
    int typ, rb0, nrb;
    if (b < 157)      { typ = 0; rb0 = b * 4;         nrb = RB_Q; }
    else if (b < 197) { typ = 1; rb0 = (b - 157) * 4; nrb = RB_S; }
    else              { typ = 2; rb0 = (b - 197) * 4; nrb = RB_S; }
    int rowblk = rb0 + w;
    bool act = rowblk < nrb;
    const ushort* src = (typ == 0) ? catQbf : catSbf;
    const ushort* Wf = Wfrag + (size_t)typ * 16384;
    const float* bias = (typ == 0) ? bq : (typ == 1) ? bk : bv;
    int rlimit = (typ == 0) ? ROWS_Q : ROWS_S;

    short8 af[8];
    if (act) {
        const ushort* ap = src + (size_t)rowblk * 4096 + lane * 8;
        #pragma unroll
        for (int ks = 0; ks < 8; ++ks) af[ks] = *(const short8*)(ap + ks * 512);
    }
    #pragma unroll
    for (int ct = 0; ct < 4; ++ct) {
        f32x16 Cm;
        #pragma unroll
        for (int r = 0; r < 16; ++r) Cm[r] = 0.f;
        if (act) {
            const ushort* bp = Wf + (size_t)(ct * 8) * 512 + lane * 8;
            #pragma unroll
            for (int ks = 0; ks < 8; ++ks) {
                short8 bf_ = *(const short8*)(bp + ks * 512);
                Cm = __builtin_amdgcn_mfma_f32_32x32x16_bf16(af[ks], bf_, Cm, 0, 0, 0);
            }
            float bcol = bias[ct * 32 + (lane & 31)];
            if (typ <= 1) {
                ushort* dstB = (typ == 0) ? Qf : Kf;
                #pragma unroll
                for (int r = 0; r < 16; ++r) {
                    int row = rowblk * 32 + (r & 3) + 8 * (r >> 2) + 4 * (lane >> 5);
                    if (row < rlimit) {
                        int c = ct * 32 + (lane & 31);
                        int st = row / 25, vv = row - st * 25;
                        size_t dst = (((size_t)st * 8 + (c >> 4)) * 64 + (vv + 32 * ((c >> 3) & 1))) * 8 + (c & 7);
                        dstB[dst] = f2bf(Cm[r] + bcol);
                    }
                }
            } else {
                #pragma unroll
                for (int r = 0; r < 16; ++r) {
                    int lrow = w * 32 + (r & 3) + 8 * (r >> 2) + 4 * (lane >> 5);
                    Vt[lrow * 136 + ct * 32 + (lane & 31)] = f2bf(Cm[r] + bcol);
                }
            }
        }
    }
    if (typ == 2) {
        __syncthreads();
        const ushort* WoF = Wfrag + (size_t)3 * 16384;
        short8 a2[8];
        if (act) {
            #pragma unroll
            for (int ks = 0; ks < 8; ++ks)
                a2[ks] = *(const short8*)(Vt + (w * 32 + (lane & 31)) * 136 + ks * 16 + (lane >> 5) * 8);
        }
        #pragma unroll
        for (int ct = 0; ct < 4; ++ct) {
            if (act) {
                f32x16 Cm;
                #pragma unroll
                for (int r = 0; r < 16; ++r) Cm[r] = 0.f;
                const ushort* bp = WoF + (size_t)(ct * 8) * 512 + lane * 8;
                #pragma unroll
                for (int ks = 0; ks < 8; ++ks) {
                    short8 bf_ = *(const short8*)(bp + ks * 512);
                    Cm = __builtin_amdgcn_mfma_f32_32x32x16_bf16(a2[ks], bf_, Cm, 0, 0, 0);
                }
                #pragma unroll
                for (int r = 0; r < 16; ++r) {
                    int row = rowblk * 32 + (r & 3) + 8 * (r >> 2) + 4 * (lane >> 5);
                    if (row < ROWS_S) {
                        int c = ct * 32 + (lane & 31);
                        int tile = row / 25, vv = row - tile * 25;
                        size_t dst = ((((size_t)tile * 4 + ct) * 2 + (vv >> 4)) * 64
                                      + ((c & 31) + 32 * ((vv & 15) >> 3))) * 8 + (vv & 7);
                        Vf[dst] = f2bf(Cm[r]);
                    }
                }
            }
        }
    }
}

// ============ kernel 3: MFMA fused attention + residual + LN ============
// 800 blocks = one per (n,t); 4 waves split m 7/6/6/6; no barriers in m-loop.
// Software-pipelined: S(m+4) MFMA chain issues inside the pfrag write->read
// latency hole of iteration m. Single K reg buffer (loaded after last use).
// ALL samples (queries + supports) write raw LN sums to att; support mean
// is folded in k_dist_loss (removes proto atomics entirely).
__global__ __launch_bounds__(256, 2) void k_attn(
    const ushort* __restrict__ Qf, const ushort* __restrict__ Kf,
    const ushort* __restrict__ Vf, const ushort* __restrict__ catC,
    const float* __restrict__ bo, float* __restrict__ att) {
    __shared__ float catb[25 * 129];          // stride 129: conflict-free scalar reads
    __shared__ float red[2][50][65];          // reduce scratch; ALIASED by pfrag in m-loop
    __shared__ ushort qls[4096];              // Q-frag tile (same for all 4 waves)
    ushort* pfragU = (ushort*)red;            // [4 wv][2 ks][64 lane][8] = 8 KB < 26 KB

    int pair = blockIdx.x;                    // n*8 + t
    int t = pair & 7;
    int tid = threadIdx.x;
    int wv = tid >> 6, lane = tid & 63;
    int q = lane & 31, half = lane >> 5;

    // stage residual tile: catb = bf16(catC) + bo
    {
        const uint* cc = (const uint*)catC + (size_t)pair * 1600;
        for (int i2 = tid; i2 < 1600; i2 += 256) {
            uint u = cc[i2];
            int r = i2 >> 6, c2 = (i2 & 63) * 2;
            catb[r * 129 + c2]     = bf2f(u & 0xffffu) + bo[c2];
            catb[r * 129 + c2 + 1] = bf2f(u >> 16) + bo[c2 + 1];
        }
    }
    // stage Q-frag tile
    {
        const uint* qp = (const uint*)(Qf + (size_t)pair * 4096);
        uint* ql = (uint*)qls;
        for (int i2 = tid; i2 < 2048; i2 += 256) ql[i2] = qp[i2];
    }
    // zero this wave's P-frag (aliased memory; key>=25 slots stay 0)
    {
        uint4 z = make_uint4(0, 0, 0, 0);
        *(uint4*)&pfragU[(((wv * 2 + 0) * 64) + lane) * 8] = z;
        *(uint4*)&pfragU[(((wv * 2 + 1) * 64) + lane) * 8] = z;
    }
    __syncthreads();

    int qc = q < 25 ? q : 24;
    float attsum[64];
    #pragma unroll
    for (int i = 0; i < 64; ++i) attsum[i] = 0.f;
    float Csc = 0.f;                          // sum over m of (-mu*rs)

    const float CEXP = (float)(1.4426950408889634 * 0.08838834764831845);

    // K-frag pipeline: kb holds K(m+4) entering each iteration.
    // Overruns (m+8 up to 32) stay inside Kf+Vf allocations — loaded, never used.
    const ushort* kbase = Kf + (size_t)t * 4096 + lane * 8;
    short8 kb[8];
    #pragma unroll
    for (int ks = 0; ks < 8; ++ks)
        kb[ks] = *(const short8*)(kbase + (size_t)wv * 32768 + ks * 512);

    f32x16 S;
    #pragma unroll
    for (int r = 0; r < 16; ++r) S[r] = 0.f;
    #pragma unroll
    for (int ks = 0; ks < 8; ++ks) {
        short8 qv = *(const short8*)(qls + ks * 512 + lane * 8);
        S = __builtin_amdgcn_mfma_f32_32x32x16_bf16(kb[ks], qv, S, 0, 0, 0);
    }
    #pragma unroll
    for (int ks = 0; ks < 8; ++ks)
        kb[ks] = *(const short8*)(kbase + (size_t)(wv + 4) * 32768 + ks * 512);

    int cnt = (wv == 0) ? 7 : 6;
    for (int mi = 0; mi < cnt; ++mi) {
        int m = wv + 4 * mi;

        // ---- softmax over keys (in-lane + pair shuffle) ----
        float p[16], mx = -3e38f;
        #pragma unroll
        for (int r = 0; r < 16; ++r) {
            int key = (r & 3) + 8 * (r >> 2) + 4 * half;
            float v = (key < 25) ? S[r] : -3e38f;
            p[r] = v; mx = fmaxf(mx, v);
        }
        mx = fmaxf(mx, __shfl_xor(mx, 32));
        float sum = 0.f;
        #pragma unroll
        for (int r = 0; r < 16; ++r) { p[r] = exp2f((p[r] - mx) * CEXP); sum += p[r]; }
        sum += __shfl_xor(sum, 32);
        float inv = 1.f / sum;

        // ---- issue V loads now (latency covered by Sn chain below) ----
        const ushort* vp = Vf + ((size_t)(m * 8 + t)) * 4096 + lane * 8;
        short8 vf0 = *(const short8*)(vp);
        short8 vf1 = *(const short8*)(vp + 512);
        short8 vf2 = *(const short8*)(vp + 1024);
        short8 vf3 = *(const short8*)(vp + 1536);
        short8 vf4 = *(const short8*)(vp + 2048);
        short8 vf5 = *(const short8*)(vp + 2560);
        short8 vf6 = *(const short8*)(vp + 3072);
        short8 vf7 = *(const short8*)(vp + 3584);

        // ---- P^T (C-layout) -> B-frag LDS write ----
        #pragma unroll
        for (int r = 0; r < 16; ++r) {
            int key = (r & 3) + 8 * (r >> 2) + 4 * half;
            if (key < 25)
                pfragU[(((wv * 2 + (key >> 4)) * 64) + (q + 32 * ((key >> 3) & 1))) * 8 + (key & 7)]
                    = f2bf(p[r] * inv);
        }

        // ---- pipelined: S(m+4) chain fills the write->read round-trip ----
        f32x16 Sn;
        #pragma unroll
        for (int r = 0; r < 16; ++r) Sn[r] = 0.f;
        #pragma unroll
        for (int ks = 0; ks < 8; ++ks) {
            short8 qv = *(const short8*)(qls + ks * 512 + lane * 8);
            Sn = __builtin_amdgcn_mfma_f32_32x32x16_bf16(kb[ks], qv, Sn, 0, 0, 0);
        }
        // prefetch K(m+8) into kb (kb's last use was the Sn chain above)
        #pragma unroll
        for (int ks = 0; ks < 8; ++ks)
            kb[ks] = *(const short8*)(kbase + (size_t)(m + 8) * 32768 + ks * 512);

        // ---- read P B-frags back ----
        short8 pb0 = *(const short8*)&pfragU[(((wv * 2 + 0) * 64) + lane) * 8];
        short8 pb1 = *(const short8*)&pfragU[(((wv * 2 + 1) * 64) + lane) * 8];

        // ---- ctx^T = Vo^T . P^T ----
        f32x16 ctx[4];
        #pragma unroll
        for (int mt = 0; mt < 4; ++mt) {
            #pragma unroll
            for (int r = 0; r < 16; ++r) ctx[mt][r] = 0.f;
        }
        ctx[0] = __builtin_amdgcn_mfma_f32_32x32x16_bf16(vf0, pb0, ctx[0], 0, 0, 0);
        ctx[0] = __builtin_amdgcn_mfma_f32_32x32x16_bf16(vf1, pb1, ctx[0], 0, 0, 0);
        ctx[1] = __builtin_amdgcn_mfma_f32_32x32x16_bf16(vf2, pb0, ctx[1], 0, 0, 0);
        ctx[1] = __builtin_amdgcn_mfma_f32_32x32x16_bf16(vf3, pb1, ctx[1], 0, 0, 0);
        ctx[2] = __builtin_amdgcn_mfma_f32_32x32x16_bf16(vf4, pb0, ctx[2], 0, 0, 0);
        ctx[2] = __builtin_amdgcn_mfma_f32_32x32x16_bf16(vf5, pb1, ctx[2], 0, 0, 0);
        ctx[3] = __builtin_amdgcn_mfma_f32_32x32x16_bf16(vf6, pb0, ctx[3], 0, 0, 0);
        ctx[3] = __builtin_amdgcn_mfma_f32_32x32x16_bf16(vf7, pb1, ctx[3], 0, 0, 0);

        // ---- x = ctx + (cat + bo); LN stats (4-way split chains) ----
        float s1 = 0.f, s2 = 0.f;
        #pragma unroll
        for (int mt = 0; mt < 4; ++mt) {
            float t1 = 0.f, t2 = 0.f;
            #pragma unroll
            for (int r = 0; r < 16; ++r) {
                int c = mt * 32 + (r & 3) + 8 * (r >> 2) + 4 * half;
                float xv = ctx[mt][r] + catb[qc * 129 + c];
                ctx[mt][r] = xv;
                t1 += xv; t2 = fmaf(xv, xv, t2);
            }
            s1 += t1; s2 += t2;
        }
        s1 += __shfl_xor(s1, 32); s2 += __shfl_xor(s2, 32);
        float mu = s1 * (1.f / 128.f);
        float var = s2 * (1.f / 128.f) - mu * mu;
        var = fmaxf(var, 0.f);
        float rs = rsqrtf(var + 1e-12f);
        #pragma unroll
        for (int i = 0; i < 64; ++i)
            attsum[i] = fmaf(ctx[i >> 4][i & 15], rs, attsum[i]);
        Csc = fmaf(-mu, rs, Csc);

        S = Sn;
    }

    // ---- 2-stage pairwise cross-wave reduction (compact: 50 live lanes) ----
    __syncthreads();   // all waves done with m-loop; pfrag alias now dead
    int s = half * 25 + q;
    bool act = q < 25;
    if ((wv == 1 || wv == 3) && act) {
        float (*rg)[65] = red[wv >> 1];
        #pragma unroll
        for (int i = 0; i < 64; ++i) rg[s][i] = attsum[i];
        rg[s][64] = Csc;
    }
    __syncthreads();
    if ((wv == 0 || wv == 2) && act) {
        float (*rg)[65] = red[wv >> 1];
        #pragma unroll
        for (int i = 0; i < 64; ++i) attsum[i] += rg[s][i];
        Csc += rg[s][64];
    }
    __syncthreads();
    if (wv == 2 && act) {
        #pragma unroll
        for (int i = 0; i < 64; ++i) red[0][s][i] = attsum[i];
        red[0][s][64] = Csc;
    }
    __syncthreads();
    if (wv == 0 && act) {
        #pragma unroll
        for (int i = 0; i < 64; ++i) attsum[i] += red[0][s][i];
        Csc += red[0][s][64];
        float* ap = att + (size_t)pair * TILE + q * 128;
        #pragma unroll
        for (int mt = 0; mt < 4; ++mt) {
            #pragma unroll
            for (int rg4 = 0; rg4 < 4; ++rg4) {
                int c0 = mt * 32 + 8 * rg4 + 4 * half;
                int i0 = mt * 16 + rg4 * 4;
                float4 o;
                o.x = attsum[i0 + 0] + Csc; o.y = attsum[i0 + 1] + Csc;
                o.z = attsum[i0 + 2] + Csc; o.w = attsum[i0 + 3] + Csc;
                *(float4*)&ap[c0] = o;
            }
        }
    }
}

// ============ kernel 4: fused distances + log-softmax loss/acc ============
// 375 blocks, one per (query, class); support mean folded on the fly.
// Last block (atomic ticket) computes loss + accuracy.
__global__ __launch_bounds__(256) void k_dist_loss(
    const float* __restrict__ att, const float* __restrict__ ln_g,
    float* __restrict__ dist, int* __restrict__ counter,
    float* __restrict__ out) {
    int b = blockIdx.x;
    int i = b / 5, j = b - 5 * i;
    const float4* a  = (const float4*)(att + (size_t)i * ROW);
    const float4* s0 = (const float4*)(att + (size_t)(NQ + j * 5 + 0) * ROW);
    const float4* s1p = (const float4*)(att + (size_t)(NQ + j * 5 + 1) * ROW);
    const float4* s2p = (const float4*)(att + (size_t)(NQ + j * 5 + 2) * ROW);
    const float4* s3p = (const float4*)(att + (size_t)(NQ + j * 5 + 3) * ROW);
    const float4* s4p = (const float4*)(att + (size_t)(NQ + j * 5 + 4) * ROW);
    float d = 0.f;
    for (int e4 = threadIdx.x; e4 < 6400; e4 += 256) {
        float4 av = a[e4];
        float4 q0 = s0[e4], q1 = s1p[e4], q2 = s2p[e4], q3 = s3p[e4], q4 = s4p[e4];
        float4 g4 = *(const float4*)(ln_g + (e4 & 31) * 4);
        float px = 0.2f * (q0.x + q1.x + q2.x + q3.x + q4.x);
        float py = 0.2f * (q0.y + q1.y + q2.y + q3.y + q4.y);
        float pz = 0.2f * (q0.z + q1.z + q2.z + q3.z + q4.z);
        float pw = 0.2f * (q0.w + q1.w + q2.w + q3.w + q4.w);
        float dx = av.x - px, dy = av.y - py, dz = av.z - pz, dw = av.w - pw;
        d = fmaf(g4.x * g4.x, dx * dx, d);
        d = fmaf(g4.y * g4.y, dy * dy, d);
        d = fmaf(g4.z * g4.z, dz * dz, d);
        d = fmaf(g4.w * g4.w, dw * dw, d);
    }
    #pragma unroll
    for (int msk = 32; msk >= 1; msk >>= 1) d += __shfl_xor(d, msk);
    __shared__ float part[4];
    __shared__ int lastFlag;
    int lane = threadIdx.x & 63, wv = threadIdx.x >> 6;
    if (lane == 0) part[wv] = d;
    __syncthreads();
    if (threadIdx.x == 0) {
        float total = (part[0] + part[1] + part[2] + part[3]) * (1.f / 625.f);
        __hip_atomic_store(&dist[b], total, __ATOMIC_RELEASE, __HIP_MEMORY_SCOPE_AGENT);
        int tk = __hip_atomic_fetch_add(counter, 1, __ATOMIC_ACQ_REL, __HIP_MEMORY_SCOPE_AGENT);
        lastFlag = (tk == 374);
    }
    __syncthreads();
    if (!lastFlag) return;

    // last block: loss + accuracy over the 375 dists
    int iq = threadIdx.x;   // 75 active
    float li = 0.f, ok = 0.f;
    if (iq < NQ) {
        float dd[5];
        #pragma unroll
        for (int jj = 0; jj < 5; ++jj)
            dd[jj] = __hip_atomic_load(&dist[iq * 5 + jj], __ATOMIC_ACQUIRE, __HIP_MEMORY_SCOPE_AGENT);
        int cls = iq / NQRY;
        float mind = dd[0];
        int best = 0;
        #pragma unroll
        for (int jj = 1; jj < 5; ++jj) {
            if (dd[jj] < mind) mind = dd[jj];
            if (dd[jj] < dd[best]) best = jj;   // first-min == argmax(-d)
        }
        float sume = 0.f;
        #pragma unroll
        for (int jj = 0; jj < 5; ++jj) sume += expf(mind - dd[jj]);
        float lse = logf(sume) - mind;
        li = dd[cls] + lse;
        ok = (best == cls) ? 1.f : 0.f;
    }
    #pragma unroll
    for (int msk = 32; msk >= 1; msk >>= 1) {
        li += __shfl_xor(li, msk);
        ok += __shfl_xor(ok, msk);
    }
    if (lane == 0) { part[wv] = li; part[wv + 2] = ok; }
    __syncthreads();
    if (threadIdx.x == 0) {
        out[0] = (part[0] + part[1]) / 75.f;
        out[1] = (part[2] + part[3]) / 75.f;
    }
}

extern "C" void kernel_launch(void* const* d_in, const int* in_sizes, int n_in,
                              void* d_out, int out_size, void* d_ws, size_t ws_size,
                              hipStream_t stream) {
    const float* input = (const float*)d_in[0];
    const float* Wq   = (const float*)d_in[1];
    const float* bq   = (const float*)d_in[2];
    const float* Wk   = (const float*)d_in[3];
    const float* bk   = (const float*)d_in[4];
    const float* Wv   = (const float*)d_in[5];
    const float* bv   = (const float*)d_in[6];
    const float* Wo   = (const float*)d_in[7];
    const float* bo   = (const float*)d_in[8];
    const float* ln_g = (const float*)d_in[9];
    const float* ln_b = (const float*)d_in[10];  // cancels in the distance
    const int* target = (const int*)d_in[11];
    float* out = (float*)d_out;
    (void)ln_b;

    float* ws = (float*)d_ws;
    ushort* catQbf = (ushort*)ws;                            // 2,560,000 u16
    ushort* catSbf = catQbf + (size_t)RB_Q * 4096;           //   643,072
    ushort* Wfrag  = catSbf + (size_t)RB_S * 4096;           //    65,536
    ushort* catC   = Wfrag + 65536;                          // 2,560,000
    ushort* Qf     = catC + 2560000;                         // 3,276,800
    ushort* Kf     = Qf + 3276800;                           //   819,200
    ushort* Vf     = Kf + 819200;                            //   819,200 (also prefetch overrun pad)
    float*  att    = (float*)(Vf + 819200);                  // 100*25600 fp32 (all samples)
    float*  distb  = att + 2560000;                          // 375
    int*    counter= (int*)(distb + 512);
    // total ~31.8 MB

    k_prep<<<204, 256, 0, stream>>>(input, target, Wq, Wk, Wv, Wo,
                                    catQbf, catSbf, Wfrag, catC, counter);
    k_proj<<<237, 256, 0, stream>>>(catQbf, catSbf, Wfrag, bq, bk, bv, Qf, Kf, Vf);
    k_attn<<<800, 256, 0, stream>>>(Qf, Kf, Vf, catC, bo, att);
    k_dist_loss<<<375, 256, 0, stream>>>(att, ln_g, distb, counter, out);
}

// Round 7
// 186.461 us; speedup vs baseline: 1.0928x; 1.0928x over previous
//
#include <hip/hip_runtime.h>
#include <math.h>

// Problem constants (fixed by reference setup_inputs)
#define NTOT 100
#define NQ   75
#define NP   25
#define CC   128
#define TT   8
#define VV   25
#define NCLS 5
#define NSUP 5
#define NQRY 15
#define ROW  (TT*VV*CC)   // 25600 floats per sample
#define TILE (VV*CC)      // 3200 floats per (n,t)
#define ROWS_Q 20000
#define ROWS_S 5000
#define RB_Q 625
#define RB_S 157

typedef __attribute__((ext_vector_type(8))) short short8;
typedef __attribute__((ext_vector_type(16))) float f32x16;

typedef union { uint4 u4; short8 s8; } pk_t;

__device__ __forceinline__ ushort f2bf(float f) {
    uint u = __float_as_uint(f);
    u += 0x7FFFu + ((u >> 16) & 1u);   // RNE
    return (ushort)(u >> 16);
}
__device__ __forceinline__ float bf2f(uint u16v) {
    return __uint_as_float(u16v << 16);
}
__device__ __forceinline__ uint pkbf(float a, float b) {
    return (uint)f2bf(a) | ((uint)f2bf(b) << 16);
}

// ============ kernel 1: prep ============
// blocks 0..199 : gather half-sample (100 tv rows) -> catC bf16 + bf16 A-frags
// blocks 200..203: weight -> bf16 B-frags; 203 also zeros supp-frag pad + ticket
__global__ __launch_bounds__(256) void k_prep(
    const float* __restrict__ input, const int* __restrict__ target,
    const float* __restrict__ Wq, const float* __restrict__ Wk,
    const float* __restrict__ Wv, const float* __restrict__ Wo,
    ushort* __restrict__ catQbf, ushort* __restrict__ catSbf,
    ushort* __restrict__ Wfrag, ushort* __restrict__ catC,
    int* __restrict__ counter) {
    __shared__ float smp[100 * 129];   // [tt][c], stride 129 conflict-free
    __shared__ int targ[NTOT];
    __shared__ int order[NTOT];
    int b = blockIdx.x, tid = threadIdx.x;

    if (b < 200) {
        int n = b >> 1, hf = b & 1;
        if (tid < NTOT) targ[tid] = target[tid];
        __syncthreads();
        if (tid < NTOT) {
            int ti = targ[tid], rank = 0;
            for (int j = 0; j < NTOT; ++j) {
                int tj = targ[j];
                rank += (tj < ti) || (tj == ti && j < tid);
            }
            order[rank] = tid;
        }
        __syncthreads();
        int src;
        if (n < NQ) { int m = n / NQRY, qq = n - m * NQRY; src = order[m * 20 + NSUP + qq]; }
        else        { int i = n - NQ; int m = i / NSUP, s = i - m * NSUP; src = order[m * 20 + s]; }

        const float* in = input + (size_t)src * ROW + hf * 100;
        for (int idx = tid; idx < 12800; idx += 256) {
            int c = idx / 100, tt = idx - c * 100;      // contiguous 400B runs
            smp[tt * 129 + c] = in[c * 200 + tt];
        }
        __syncthreads();
        // catC bf16 [n][tv][c], packed u32 writes (coalesced)
        uint* cc = (uint*)catC + ((size_t)n * 200 + hf * 100) * 64;
        for (int e2 = tid; e2 < 6400; e2 += 256) {
            int r = e2 >> 6, c2 = e2 & 63;
            cc[r * 64 + c2] = pkbf(smp[r * 129 + c2 * 2], smp[r * 129 + c2 * 2 + 1]);
        }
        // bf16 A-frag writes
        bool isSup = (n >= NQ);
        for (int o = tid; o < 1600; o += 256) {
            int k8 = o / 100, tt = o - k8 * 100;
            int base = tt * 129 + k8 * 8;
            uint4 pk;
            pk.x = pkbf(smp[base+0], smp[base+1]);
            pk.y = pkbf(smp[base+2], smp[base+3]);
            pk.z = pkbf(smp[base+4], smp[base+5]);
            pk.w = pkbf(smp[base+6], smp[base+7]);
            int row = n * 200 + hf * 100 + tt;
            size_t dst = (((size_t)(row >> 5) * 8 + (k8 >> 1)) * 64 + ((row & 31) + 32 * (k8 & 1))) * 8;
            *(uint4*)(catQbf + dst) = pk;
            if (isSup) {
                int r2 = (n - NQ) * 200 + hf * 100 + tt;
                size_t dst2 = (((size_t)(r2 >> 5) * 8 + (k8 >> 1)) * 64 + ((r2 & 31) + 32 * (k8 & 1))) * 8;
                *(uint4*)(catSbf + dst2) = pk;
            }
        }
    } else {
        int wi = b - 200;
        const float* W = (wi == 0) ? Wq : (wi == 1) ? Wk : (wi == 2) ? Wv : Wo;
        ushort* dstW = Wfrag + (size_t)wi * 16384;
        for (int o = tid; o < 2048; o += 256) {
            int k8 = o >> 7, c = o & 127;
            uint4 pk;
            pk.x = pkbf(W[(k8*8+0)*128 + c], W[(k8*8+1)*128 + c]);
            pk.y = pkbf(W[(k8*8+2)*128 + c], W[(k8*8+3)*128 + c]);
            pk.z = pkbf(W[(k8*8+4)*128 + c], W[(k8*8+5)*128 + c]);
            pk.w = pkbf(W[(k8*8+6)*128 + c], W[(k8*8+7)*128 + c]);
            size_t dst = ((size_t)((c >> 5) * 8 + (k8 >> 1)) * 64 + ((c & 31) + 32 * (k8 & 1))) * 8;
            *(uint4*)(dstW + dst) = pk;
        }
        if (wi == 3) {
            uint4 z = make_uint4(0, 0, 0, 0);
            for (int o = tid; o < 512; o += 256) {
                int ks = o >> 6, l = o & 63;
                if ((l & 31) >= 8)
                    *(uint4*)(catSbf + (((size_t)156 * 8 + ks) * 64 + l) * 8) = z;
            }
            if (tid == 0) *counter = 0;
        }
    }
}

// ============ kernel 2: projections via MFMA ============
__global__ __launch_bounds__(256) void k_proj(
    const ushort* __restrict__ catQbf, const ushort* __restrict__ catSbf,
    const ushort* __restrict__ Wfrag, const float* __restrict__ bq,
    const float* __restrict__ bk, const float* __restrict__ bv,
    ushort* __restrict__ Qf, ushort* __restrict__ Kf, ushort* __restrict__ Vf) {
    __shared__ ushort Vt[128 * 136];
    int b = blockIdx.x, tid = threadIdx.x;
    int w = tid >> 6, lane = tid & 63;
    int typ, rb0, nrb;
    if (b < 157)      { typ = 0; rb0 = b * 4;         nrb = RB_Q; }
    else if (b < 197) { typ = 1; rb0 = (b - 157) * 4; nrb = RB_S; }
    else              { typ = 2; rb0 = (b - 197) * 4; nrb = RB_S; }
    int rowblk = rb0 + w;
    bool act = rowblk < nrb;
    const ushort* src = (typ == 0) ? catQbf : catSbf;
    const ushort* Wf = Wfrag + (size_t)typ * 16384;
    const float* bias = (typ == 0) ? bq : (typ == 1) ? bk : bv;
    int rlimit = (typ == 0) ? ROWS_Q : ROWS_S;

    short8 af[8];
    if (act) {
        const ushort* ap = src + (size_t)rowblk * 4096 + lane * 8;
        #pragma unroll
        for (int ks = 0; ks < 8; ++ks) af[ks] = *(const short8*)(ap + ks * 512);
    }
    #pragma unroll
    for (int ct = 0; ct < 4; ++ct) {
        f32x16 Cm;
        #pragma unroll
        for (int r = 0; r < 16; ++r) Cm[r] = 0.f;
        if (act) {
            const ushort* bp = Wf + (size_t)(ct * 8) * 512 + lane * 8;
            #pragma unroll
            for (int ks = 0; ks < 8; ++ks) {
                short8 bf_ = *(const short8*)(bp + ks * 512);
                Cm = __builtin_amdgcn_mfma_f32_32x32x16_bf16(af[ks], bf_, Cm, 0, 0, 0);
            }
            float bcol = bias[ct * 32 + (lane & 31)];
            if (typ <= 1) {
                ushort* dstB = (typ == 0) ? Qf : Kf;
                #pragma unroll
                for (int r = 0; r < 16; ++r) {
                    int row = rowblk * 32 + (r & 3) + 8 * (r >> 2) + 4 * (lane >> 5);
                    if (row < rlimit) {
                        int c = ct * 32 + (lane & 31);
                        int st = row / 25, vv = row - st * 25;
                        size_t dst = (((size_t)st * 8 + (c >> 4)) * 64 + (vv + 32 * ((c >> 3) & 1))) * 8 + (c & 7);
                        dstB[dst] = f2bf(Cm[r] + bcol);
                    }
                }
            } else {
                #pragma unroll
                for (int r = 0; r < 16; ++r) {
                    int lrow = w * 32 + (r & 3) + 8 * (r >> 2) + 4 * (lane >> 5);
                    Vt[lrow * 136 + ct * 32 + (lane & 31)] = f2bf(Cm[r] + bcol);
                }
            }
        }
    }
    if (typ == 2) {
        __syncthreads();
        const ushort* WoF = Wfrag + (size_t)3 * 16384;
        short8 a2[8];
        if (act) {
            #pragma unroll
            for (int ks = 0; ks < 8; ++ks)
                a2[ks] = *(const short8*)(Vt + (w * 32 + (lane & 31)) * 136 + ks * 16 + (lane >> 5) * 8);
        }
        #pragma unroll
        for (int ct = 0; ct < 4; ++ct) {
            if (act) {
                f32x16 Cm;
                #pragma unroll
                for (int r = 0; r < 16; ++r) Cm[r] = 0.f;
                const ushort* bp = WoF + (size_t)(ct * 8) * 512 + lane * 8;
                #pragma unroll
                for (int ks = 0; ks < 8; ++ks) {
                    short8 bf_ = *(const short8*)(bp + ks * 512);
                    Cm = __builtin_amdgcn_mfma_f32_32x32x16_bf16(a2[ks], bf_, Cm, 0, 0, 0);
                }
                #pragma unroll
                for (int r = 0; r < 16; ++r) {
                    int row = rowblk * 32 + (r & 3) + 8 * (r >> 2) + 4 * (lane >> 5);
                    if (row < ROWS_S) {
                        int c = ct * 32 + (lane & 31);
                        int tile = row / 25, vv = row - tile * 25;
                        size_t dst = ((((size_t)tile * 4 + ct) * 2 + (vv >> 4)) * 64
                                      + ((c & 31) + 32 * ((vv & 15) >> 3))) * 8 + (vv & 7);
                        Vf[dst] = f2bf(Cm[r]);
                    }
                }
            }
        }
    }
}

// ============ kernel 3: MFMA fused attention + residual + LN ============
// 800 blocks = one per (n,t); 4 waves split m 7/6/6/6; no barriers in m-loop.
// P C-layout -> B-frag via 4 shfl_xor(32) (half<->half exchange) — no LDS
// roundtrip, no bank conflicts, no zero-init (exp2(-inf)=0 masks keys>=25).
// No Sn pipelining (R6: spilled). All samples write raw LN sums to att.
__global__ __launch_bounds__(256, 2) void k_attn(
    const ushort* __restrict__ Qf, const ushort* __restrict__ Kf,
    const ushort* __restrict__ Vf, const ushort* __restrict__ catC,
    const float* __restrict__ bo, float* __restrict__ att) {
    __shared__ float catb[25 * 129];          // stride 129: conflict-free scalar reads
    __shared__ float red[2][50][65];          // epilogue reduce scratch
    __shared__ ushort qls[4096];              // Q-frag tile (shared by all 4 waves)

    int pair = blockIdx.x;                    // n*8 + t
    int t = pair & 7;
    int tid = threadIdx.x;
    int wv = tid >> 6, lane = tid & 63;
    int q = lane & 31, half = lane >> 5;

    // stage residual tile: catb = bf16(catC) + bo
    {
        const uint* cc = (const uint*)catC + (size_t)pair * 1600;
        for (int i2 = tid; i2 < 1600; i2 += 256) {
            uint u = cc[i2];
            int r = i2 >> 6, c2 = (i2 & 63) * 2;
            catb[r * 129 + c2]     = bf2f(u & 0xffffu) + bo[c2];
            catb[r * 129 + c2 + 1] = bf2f(u >> 16) + bo[c2 + 1];
        }
    }
    // stage Q-frag tile
    {
        const uint* qp = (const uint*)(Qf + (size_t)pair * 4096);
        uint* ql = (uint*)qls;
        for (int i2 = tid; i2 < 2048; i2 += 256) ql[i2] = qp[i2];
    }
    __syncthreads();

    int qc = q < 25 ? q : 24;
    float attsum[64];
    #pragma unroll
    for (int i = 0; i < 64; ++i) attsum[i] = 0.f;
    float Csc = 0.f;                          // sum over m of (-mu*rs)

    const float CEXP = (float)(1.4426950408889634 * 0.08838834764831845);

    // K-frag double buffer: kf holds K(m); overruns land in Vf region (unused)
    const ushort* kbase = Kf + (size_t)t * 4096 + lane * 8;
    short8 kf[8];
    #pragma unroll
    for (int ks = 0; ks < 8; ++ks)
        kf[ks] = *(const short8*)(kbase + (size_t)wv * 32768 + ks * 512);

    int cnt = (wv == 0) ? 7 : 6;
    for (int mi = 0; mi < cnt; ++mi) {
        int m = wv + 4 * mi;

        // ---- S^T = K . Q^T  (Q from LDS, K from prefetched regs) ----
        f32x16 S;
        #pragma unroll
        for (int r = 0; r < 16; ++r) S[r] = 0.f;
        #pragma unroll
        for (int ks = 0; ks < 8; ++ks) {
            short8 qv = *(const short8*)(qls + ks * 512 + lane * 8);
            S = __builtin_amdgcn_mfma_f32_32x32x16_bf16(kf[ks], qv, S, 0, 0, 0);
        }

        // ---- softmax over keys (in-lane + pair shuffle) ----
        float p[16], mx = -3e38f;
        #pragma unroll
        for (int r = 0; r < 16; ++r) {
            int key = (r & 3) + 8 * (r >> 2) + 4 * half;
            float v = (key < 25) ? S[r] : -3e38f;
            p[r] = v; mx = fmaxf(mx, v);
        }
        mx = fmaxf(mx, __shfl_xor(mx, 32));
        float sum = 0.f;
        #pragma unroll
        for (int r = 0; r < 16; ++r) { p[r] = exp2f((p[r] - mx) * CEXP); sum += p[r]; }
        sum += __shfl_xor(sum, 32);
        float inv = 1.f / sum;

        // ---- issue V loads (latency covered by shuffle transform below) ----
        const ushort* vp = Vf + ((size_t)(m * 8 + t)) * 4096 + lane * 8;
        short8 vf0 = *(const short8*)(vp);
        short8 vf1 = *(const short8*)(vp + 512);
        short8 vf2 = *(const short8*)(vp + 1024);
        short8 vf3 = *(const short8*)(vp + 1536);
        short8 vf4 = *(const short8*)(vp + 2048);
        short8 vf5 = *(const short8*)(vp + 2560);
        short8 vf6 = *(const short8*)(vp + 3072);
        short8 vf7 = *(const short8*)(vp + 3584);
        // ---- prefetch K(m+4) (last use of kf was the S chain above) ----
        #pragma unroll
        for (int ks = 0; ks < 8; ++ks)
            kf[ks] = *(const short8*)(kbase + (size_t)(m + 4) * 32768 + ks * 512);

        // ---- P: C-layout -> B-frag via half<->half shfl_xor(32) ----
        // value for key k, col q lives in lane q+32*((k>>2)&1), reg (k&3)+4*(k>>3)
        uint o01   = pkbf(p[0] * inv,  p[1] * inv);
        uint o23   = pkbf(p[2] * inv,  p[3] * inv);
        uint o45   = pkbf(p[4] * inv,  p[5] * inv);
        uint o67   = pkbf(p[6] * inv,  p[7] * inv);
        uint o89   = pkbf(p[8] * inv,  p[9] * inv);
        uint o1011 = pkbf(p[10] * inv, p[11] * inv);
        uint o1213 = pkbf(p[12] * inv, p[13] * inv);
        uint o1415 = pkbf(p[14] * inv, p[15] * inv);
        bool h0 = (half == 0);
        uint rA = __shfl_xor(h0 ? o45 : o01, 32);     // h0 gets partner r01; h1 gets partner r45
        uint rB = __shfl_xor(h0 ? o67 : o23, 32);
        uint rC = __shfl_xor(h0 ? o1213 : o89, 32);
        uint rD = __shfl_xor(h0 ? o1415 : o1011, 32);
        pk_t P0, P1;
        P0.u4 = h0 ? make_uint4(o01, o23, rA, rB) : make_uint4(rA, rB, o45, o67);
        P1.u4 = h0 ? make_uint4(o89, o1011, rC, rD) : make_uint4(rC, rD, o1213, o1415);
        short8 pb0 = P0.s8, pb1 = P1.s8;

        // ---- ctx^T = Vo^T . P^T ----
        f32x16 ctx[4];
        #pragma unroll
        for (int mt = 0; mt < 4; ++mt) {
            #pragma unroll
            for (int r = 0; r < 16; ++r) ctx[mt][r] = 0.f;
        }
        ctx[0] = __builtin_amdgcn_mfma_f32_32x32x16_bf16(vf0, pb0, ctx[0], 0, 0, 0);
        ctx[0] = __builtin_amdgcn_mfma_f32_32x32x16_bf16(vf1, pb1, ctx[0], 0, 0, 0);
        ctx[1] = __builtin_amdgcn_mfma_f32_32x32x16_bf16(vf2, pb0, ctx[1], 0, 0, 0);
        ctx[1] = __builtin_amdgcn_mfma_f32_32x32x16_bf16(vf3, pb1, ctx[1], 0, 0, 0);
        ctx[2] = __builtin_amdgcn_mfma_f32_32x32x16_bf16(vf4, pb0, ctx[2], 0, 0, 0);
        ctx[2] = __builtin_amdgcn_mfma_f32_32x32x16_bf16(vf5, pb1, ctx[2], 0, 0, 0);
        ctx[3] = __builtin_amdgcn_mfma_f32_32x32x16_bf16(vf6, pb0, ctx[3], 0, 0, 0);
        ctx[3] = __builtin_amdgcn_mfma_f32_32x32x16_bf16(vf7, pb1, ctx[3], 0, 0, 0);

        // ---- x = ctx + (cat + bo); LN stats (split chains); accumulate ----
        float s1 = 0.f, s2 = 0.f;
        #pragma unroll
        for (int mt = 0; mt < 4; ++mt) {
            float t1 = 0.f, t2 = 0.f;
            #pragma unroll
            for (int r = 0; r < 16; ++r) {
                int c = mt * 32 + (r & 3) + 8 * (r >> 2) + 4 * half;
                float xv = ctx[mt][r] + catb[qc * 129 + c];
                ctx[mt][r] = xv;
                t1 += xv; t2 = fmaf(xv, xv, t2);
            }
            s1 += t1; s2 += t2;
        }
        s1 += __shfl_xor(s1, 32); s2 += __shfl_xor(s2, 32);
        float mu = s1 * (1.f / 128.f);
        float var = s2 * (1.f / 128.f) - mu * mu;
        var = fmaxf(var, 0.f);
        float rs = rsqrtf(var + 1e-12f);
        #pragma unroll
        for (int i = 0; i < 64; ++i)
            attsum[i] = fmaf(ctx[i >> 4][i & 15], rs, attsum[i]);
        Csc = fmaf(-mu, rs, Csc);
    }

    // ---- 2-stage pairwise cross-wave reduction (compact: 50 live lanes) ----
    __syncthreads();
    int s = half * 25 + q;
    bool act = q < 25;
    if ((wv == 1 || wv == 3) && act) {
        float (*rg)[65] = red[wv >> 1];
        #pragma unroll
        for (int i = 0; i < 64; ++i) rg[s][i] = attsum[i];
        rg[s][64] = Csc;
    }
    __syncthreads();
    if ((wv == 0 || wv == 2) && act) {
        float (*rg)[65] = red[wv >> 1];
        #pragma unroll
        for (int i = 0; i < 64; ++i) attsum[i] += rg[s][i];
        Csc += rg[s][64];
    }
    __syncthreads();
    if (wv == 2 && act) {
        #pragma unroll
        for (int i = 0; i < 64; ++i) red[0][s][i] = attsum[i];
        red[0][s][64] = Csc;
    }
    __syncthreads();
    if (wv == 0 && act) {
        #pragma unroll
        for (int i = 0; i < 64; ++i) attsum[i] += red[0][s][i];
        Csc += red[0][s][64];
        float* ap = att + (size_t)pair * TILE + q * 128;
        #pragma unroll
        for (int mt = 0; mt < 4; ++mt) {
            #pragma unroll
            for (int rg4 = 0; rg4 < 4; ++rg4) {
                int c0 = mt * 32 + 8 * rg4 + 4 * half;
                int i0 = mt * 16 + rg4 * 4;
                float4 o;
                o.x = attsum[i0 + 0] + Csc; o.y = attsum[i0 + 1] + Csc;
                o.z = attsum[i0 + 2] + Csc; o.w = attsum[i0 + 3] + Csc;
                *(float4*)&ap[c0] = o;
            }
        }
    }
}

// ============ kernel 4: fused distances + log-softmax loss/acc ============
// 375 blocks, one per (query, class); support mean folded on the fly.
// Last block (atomic ticket) computes loss + accuracy.
__global__ __launch_bounds__(256) void k_dist_loss(
    const float* __restrict__ att, const float* __restrict__ ln_g,
    float* __restrict__ dist, int* __restrict__ counter,
    float* __restrict__ out) {
    int b = blockIdx.x;
    int i = b / 5, j = b - 5 * i;
    const float4* a  = (const float4*)(att + (size_t)i * ROW);
    const float4* s0 = (const float4*)(att + (size_t)(NQ + j * 5 + 0) * ROW);
    const float4* s1p = (const float4*)(att + (size_t)(NQ + j * 5 + 1) * ROW);
    const float4* s2p = (const float4*)(att + (size_t)(NQ + j * 5 + 2) * ROW);
    const float4* s3p = (const float4*)(att + (size_t)(NQ + j * 5 + 3) * ROW);
    const float4* s4p = (const float4*)(att + (size_t)(NQ + j * 5 + 4) * ROW);
    float d = 0.f;
    for (int e4 = threadIdx.x; e4 < 6400; e4 += 256) {
        float4 av = a[e4];
        float4 q0 = s0[e4], q1 = s1p[e4], q2 = s2p[e4], q3 = s3p[e4], q4 = s4p[e4];
        float4 g4 = *(const float4*)(ln_g + (e4 & 31) * 4);
        float px = 0.2f * (q0.x + q1.x + q2.x + q3.x + q4.x);
        float py = 0.2f * (q0.y + q1.y + q2.y + q3.y + q4.y);
        float pz = 0.2f * (q0.z + q1.z + q2.z + q3.z + q4.z);
        float pw = 0.2f * (q0.w + q1.w + q2.w + q3.w + q4.w);
        float dx = av.x - px, dy = av.y - py, dz = av.z - pz, dw = av.w - pw;
        d = fmaf(g4.x * g4.x, dx * dx, d);
        d = fmaf(g4.y * g4.y, dy * dy, d);
        d = fmaf(g4.z * g4.z, dz * dz, d);
        d = fmaf(g4.w * g4.w, dw * dw, d);
    }
    #pragma unroll
    for (int msk = 32; msk >= 1; msk >>= 1) d += __shfl_xor(d, msk);
    __shared__ float part[4];
    __shared__ int lastFlag;
    int lane = threadIdx.x & 63, wv = threadIdx.x >> 6;
    if (lane == 0) part[wv] = d;
    __syncthreads();
    if (threadIdx.x == 0) {
        float total = (part[0] + part[1] + part[2] + part[3]) * (1.f / 625.f);
        __hip_atomic_store(&dist[b], total, __ATOMIC_RELEASE, __HIP_MEMORY_SCOPE_AGENT);
        int tk = __hip_atomic_fetch_add(counter, 1, __ATOMIC_ACQ_REL, __HIP_MEMORY_SCOPE_AGENT);
        lastFlag = (tk == 374);
    }
    __syncthreads();
    if (!lastFlag) return;

    // last block: loss + accuracy over the 375 dists
    int iq = threadIdx.x;   // 75 active
    float li = 0.f, ok = 0.f;
    if (iq < NQ) {
        float dd[5];
        #pragma unroll
        for (int jj = 0; jj < 5; ++jj)
            dd[jj] = __hip_atomic_load(&dist[iq * 5 + jj], __ATOMIC_ACQUIRE, __HIP_MEMORY_SCOPE_AGENT);
        int cls = iq / NQRY;
        float mind = dd[0];
        int best = 0;
        #pragma unroll
        for (int jj = 1; jj < 5; ++jj) {
            if (dd[jj] < mind) mind = dd[jj];
            if (dd[jj] < dd[best]) best = jj;   // first-min == argmax(-d)
        }
        float sume = 0.f;
        #pragma unroll
        for (int jj = 0; jj < 5; ++jj) sume += expf(mind - dd[jj]);
        float lse = logf(sume) - mind;
        li = dd[cls] + lse;
        ok = (best == cls) ? 1.f : 0.f;
    }
    #pragma unroll
    for (int msk = 32; msk >= 1; msk >>= 1) {
        li += __shfl_xor(li, msk);
        ok += __shfl_xor(ok, msk);
    }
    if (lane == 0) { part[wv] = li; part[wv + 2] = ok; }
    __syncthreads();
    if (threadIdx.x == 0) {
        out[0] = (part[0] + part[1]) / 75.f;
        out[1] = (part[2] + part[3]) / 75.f;
    }
}

extern "C" void kernel_launch(void* const* d_in, const int* in_sizes, int n_in,
                              void* d_out, int out_size, void* d_ws, size_t ws_size,
                              hipStream_t stream) {
    const float* input = (const float*)d_in[0];
    const float* Wq   = (const float*)d_in[1];
    const float* bq   = (const float*)d_in[2];
    const float* Wk   = (const float*)d_in[3];
    const float* bk   = (const float*)d_in[4];
    const float* Wv   = (const float*)d_in[5];
    const float* bv   = (const float*)d_in[6];
    const float* Wo   = (const float*)d_in[7];
    const float* bo   = (const float*)d_in[8];
    const float* ln_g = (const float*)d_in[9];
    const float* ln_b = (const float*)d_in[10];  // cancels in the distance
    const int* target = (const int*)d_in[11];
    float* out = (float*)d_out;
    (void)ln_b;

    float* ws = (float*)d_ws;
    ushort* catQbf = (ushort*)ws;                            // 2,560,000 u16
    ushort* catSbf = catQbf + (size_t)RB_Q * 4096;           //   643,072
    ushort* Wfrag  = catSbf + (size_t)RB_S * 4096;           //    65,536
    ushort* catC   = Wfrag + 65536;                          // 2,560,000
    ushort* Qf     = catC + 2560000;                         // 3,276,800
    ushort* Kf     = Qf + 3276800;                           //   819,200
    ushort* Vf     = Kf + 819200;                            //   819,200 (also prefetch overrun pad)
    float*  att    = (float*)(Vf + 819200);                  // 100*25600 fp32 (all samples)
    float*  distb  = att + 2560000;                          // 375
    int*    counter= (int*)(distb + 512);
    // total ~31.8 MB

    k_prep<<<204, 256, 0, stream>>>(input, target, Wq, Wk, Wv, Wo,
                                    catQbf, catSbf, Wfrag, catC, counter);
    k_proj<<<237, 256, 0, stream>>>(catQbf, catSbf, Wfrag, bq, bk, bv, Qf, Kf, Vf);
    k_attn<<<800, 256, 0, stream>>>(Qf, Kf, Vf, catC, bo, att);
    k_dist_loss<<<375, 256, 0, stream>>>(att, ln_g, distb, counter, out);
}